// Round 2
// baseline (465.136 us; speedup 1.0000x reference)
//
#include <hip/hip_runtime.h>
#include <hip/hip_bf16.h>
#include <stdint.h>

#define NB 8
#define NSEQ 1024
#define DIMM 768
#define NHEADS 12
#define DH 64
#define NQKV 2304
#define ALPHA_ 0.25f
#define SCALE_ 0.125f
#define EPS_ 1e-5f

typedef __bf16 bf16;
typedef bf16 bf16x8 __attribute__((ext_vector_type(8)));
typedef bf16 bf16x4 __attribute__((ext_vector_type(4)));
typedef float f32x4 __attribute__((ext_vector_type(4)));

#define MFMA16(a, b, c) __builtin_amdgcn_mfma_f32_16x16x32_bf16((a), (b), (c), 0, 0, 0)

static __device__ __forceinline__ void load_lds16(const void* gsrc, void* ldst) {
  __builtin_amdgcn_global_load_lds(
      (__attribute__((address_space(1))) void*)gsrc,
      (__attribute__((address_space(3))) void*)ldst, 16, 0, 0);
}

// ---------------- LayerNorm + bf16 cast: x(8192x768) -> xn bf16 ----------------
__global__ __launch_bounds__(256) void ln_kernel(
    const float* __restrict__ x, const float* __restrict__ gamma,
    const float* __restrict__ beta, bf16* __restrict__ xn) {
  const int row = blockIdx.x * 4 + (threadIdx.x >> 6);
  const int lane = threadIdx.x & 63;
  const float* xr = x + (size_t)row * DIMM;
  float4 v[3];
  float s = 0.f, s2 = 0.f;
#pragma unroll
  for (int c = 0; c < 3; ++c) {
    v[c] = *reinterpret_cast<const float4*>(xr + c * 256 + lane * 4);
    s += v[c].x + v[c].y + v[c].z + v[c].w;
    s2 += v[c].x * v[c].x + v[c].y * v[c].y + v[c].z * v[c].z + v[c].w * v[c].w;
  }
#pragma unroll
  for (int m = 1; m < 64; m <<= 1) {
    s += __shfl_xor(s, m);
    s2 += __shfl_xor(s2, m);
  }
  const float mu = s * (1.f / DIMM);
  const float rstd = rsqrtf(s2 * (1.f / DIMM) - mu * mu + EPS_);
#pragma unroll
  for (int c = 0; c < 3; ++c) {
    const float4 g4 = *reinterpret_cast<const float4*>(gamma + c * 256 + lane * 4);
    const float4 b4 = *reinterpret_cast<const float4*>(beta + c * 256 + lane * 4);
    bf16x4 o;
    o[0] = (bf16)((v[c].x - mu) * rstd * g4.x + b4.x);
    o[1] = (bf16)((v[c].y - mu) * rstd * g4.y + b4.y);
    o[2] = (bf16)((v[c].z - mu) * rstd * g4.z + b4.z);
    o[3] = (bf16)((v[c].w - mu) * rstd * g4.w + b4.w);
    *reinterpret_cast<bf16x4*>(xn + (size_t)row * DIMM + c * 256 + lane * 4) = o;
  }
}

// ------------- transpose + cast: f32 in[R][C] -> bf16 out[C][R] -------------
__global__ __launch_bounds__(256) void tcast_kernel(
    const float* __restrict__ in, bf16* __restrict__ out, int R, int C) {
  __shared__ float tile[32][33];
  const int tx = threadIdx.x & 31, ty = threadIdx.x >> 5;
  const int c0 = blockIdx.x * 32, r0 = blockIdx.y * 32;
#pragma unroll
  for (int i = ty; i < 32; i += 8)
    tile[i][tx] = in[(size_t)(r0 + i) * C + c0 + tx];
  __syncthreads();
#pragma unroll
  for (int i = ty; i < 32; i += 8)
    out[(size_t)(c0 + i) * R + r0 + tx] = (bf16)tile[tx][i];
}

// -------- QKV GEMM: xn(8192x768) @ wT(2304 cols x 768 k) -> q,k,vT bf16 --------
__global__ __launch_bounds__(256) void qkv_gemm(
    const bf16* __restrict__ xn, const bf16* __restrict__ wT,
    bf16* __restrict__ qb, bf16* __restrict__ kb, bf16* __restrict__ vt) {
  __shared__ __align__(16) bf16 As[128 * 32];
  __shared__ __align__(16) bf16 Bs[64 * 32];
  const int tid = threadIdx.x;
  const int wv = tid >> 6, l = tid & 63;
  const int l16 = l & 15, q4 = l >> 4;
  const int c0 = blockIdx.x * 64, row0 = blockIdx.y * 128;
  const int sr = tid >> 2, skk = (tid & 3) * 8;
  f32x4 acc0[4], acc1[4];
#pragma unroll
  for (int c = 0; c < 4; ++c) {
    acc0[c] = f32x4{0.f, 0.f, 0.f, 0.f};
    acc1[c] = f32x4{0.f, 0.f, 0.f, 0.f};
  }
  for (int k0 = 0; k0 < DIMM; k0 += 32) {
    __syncthreads();
    load_lds16(xn + (size_t)(row0 + sr) * DIMM + k0 + skk, As + tid * 8);
    load_lds16(xn + (size_t)(row0 + 64 + sr) * DIMM + k0 + skk, As + 2048 + tid * 8);
    load_lds16(wT + (size_t)(c0 + sr) * DIMM + k0 + skk, Bs + tid * 8);
    __syncthreads();
    const bf16x8 a0 = *reinterpret_cast<const bf16x8*>(&As[(wv * 32 + l16) * 32 + q4 * 8]);
    const bf16x8 a1 = *reinterpret_cast<const bf16x8*>(&As[(wv * 32 + 16 + l16) * 32 + q4 * 8]);
#pragma unroll
    for (int c = 0; c < 4; ++c) {
      const bf16x8 bb = *reinterpret_cast<const bf16x8*>(&Bs[(c * 16 + l16) * 32 + q4 * 8]);
      acc0[c] = MFMA16(a0, bb, acc0[c]);
      acc1[c] = MFMA16(a1, bb, acc1[c]);
    }
  }
  const int sect = c0 / DIMM;          // 0=q 1=k 2=v (uniform per block)
  const int head = (c0 % DIMM) >> 6;   // uniform per block
#pragma unroll
  for (int c = 0; c < 4; ++c) {
    const int dd = c * 16 + l16;
#pragma unroll
    for (int r = 0; r < 4; ++r) {
#pragma unroll
      for (int rsub = 0; rsub < 2; ++rsub) {
        const int gm = row0 + wv * 32 + rsub * 16 + q4 * 4 + r;
        const int b = gm >> 10, n = gm & 1023;
        const size_t bhh = (size_t)b * NHEADS + head;
        const float av = rsub ? acc1[c][r] : acc0[c][r];
        const bf16 val = (bf16)av;
        if (sect == 0)      qb[(bhh * NSEQ + n) * DH + dd] = val;
        else if (sect == 1) kb[(bhh * NSEQ + n) * DH + dd] = val;
        else                vt[(bhh * DH + dd) * NSEQ + n] = val;
      }
    }
  }
}

// -------- fused attention: per (bh, 64-row tile); writes blended + attn_out --------
// No __syncthreads: all LDS (plds[wv]) and h-prefetch state are wave-private.
// h is prefetched one j-tile ahead into registers (ping-pong hA/hB, static idx).
__global__ __launch_bounds__(256) void attn_kernel(
    const bf16* __restrict__ qb, const bf16* __restrict__ kb,
    const bf16* __restrict__ vt, const float* __restrict__ h,
    float* __restrict__ blended, bf16* __restrict__ attn_out) {
  __shared__ __align__(16) bf16 plds[4][16 * 64];
  const int tid = threadIdx.x;
  const int wv = tid >> 6, l = tid & 63;
  const int l16 = l & 15, q4 = l >> 4;
  const int i0 = blockIdx.x * 64 + wv * 16;
  const int bh = blockIdx.y;
  const float* hbase = h + ((size_t)bh << 20) + (size_t)(i0 + q4 * 4) * NSEQ + l16;
  float* bbase = blended + ((size_t)bh << 20) + (size_t)(i0 + q4 * 4) * NSEQ + l16;
  const bf16* kbase = kb + (size_t)bh * NSEQ * DH;
  const bf16* vbase = vt + (size_t)bh * DH * NSEQ;

  bf16x8 aq[2];
#pragma unroll
  for (int w2 = 0; w2 < 2; ++w2)
    aq[w2] = *reinterpret_cast<const bf16x8*>(
        qb + ((size_t)bh * NSEQ + i0 + l16) * DH + w2 * 32 + q4 * 8);

  f32x4 acc[4];
  float m_run[4], l_run[4];
#pragma unroll
  for (int r = 0; r < 4; ++r) { m_run[r] = -1e30f; l_run[r] = 0.f; }
#pragma unroll
  for (int f = 0; f < 4; ++f) acc[f] = f32x4{0.f, 0.f, 0.f, 0.f};

  bf16* pw = plds[wv];

  auto LOADH = [&](int jt, float* dst) {
#pragma unroll
    for (int js = 0; js < 4; ++js)
#pragma unroll
      for (int r = 0; r < 4; ++r)
        dst[js * 4 + r] = hbase[(size_t)r * NSEQ + jt * 64 + js * 16];
  };

  auto BODY = [&](int jt, const float* hc) {
    const int j0 = jt * 64;
    f32x4 s[4];
#pragma unroll
    for (int js = 0; js < 4; ++js) s[js] = f32x4{0.f, 0.f, 0.f, 0.f};
#pragma unroll
    for (int js = 0; js < 4; ++js) {
#pragma unroll
      for (int w2 = 0; w2 < 2; ++w2) {
        const bf16x8 kf = *reinterpret_cast<const bf16x8*>(
            kbase + (size_t)(j0 + js * 16 + l16) * DH + w2 * 32 + q4 * 8);
        s[js] = MFMA16(aq[w2], kf, s[js]);
      }
    }
    float bl[4][4];
    float tmax[4] = {-1e30f, -1e30f, -1e30f, -1e30f};
#pragma unroll
    for (int js = 0; js < 4; ++js) {
#pragma unroll
      for (int r = 0; r < 4; ++r) {
        const float val = s[js][r] * (ALPHA_ * SCALE_) + 0.75f * hc[js * 4 + r];
        bbase[(size_t)r * NSEQ + j0 + js * 16] = val;
        bl[js][r] = val;
        tmax[r] = fmaxf(tmax[r], val);
      }
    }
#pragma unroll
    for (int r = 0; r < 4; ++r) {
#pragma unroll
      for (int mm = 1; mm < 16; mm <<= 1)
        tmax[r] = fmaxf(tmax[r], __shfl_xor(tmax[r], mm));
    }
    float rsum[4] = {0.f, 0.f, 0.f, 0.f};
#pragma unroll
    for (int r = 0; r < 4; ++r) {
      const float mnew = fmaxf(m_run[r], tmax[r]);
      const float sc = __expf(m_run[r] - mnew);
      m_run[r] = mnew;
      l_run[r] *= sc;
#pragma unroll
      for (int f = 0; f < 4; ++f) acc[f][r] *= sc;
      const int prow = q4 * 4 + r;
#pragma unroll
      for (int js = 0; js < 4; ++js) {
        const float p = __expf(bl[js][r] - mnew);
        rsum[r] += p;
        const int blk = (js * 2 + (l16 >> 3)) ^ (prow & 7);
        pw[prow * 64 + blk * 8 + (l16 & 7)] = (bf16)p;
      }
    }
#pragma unroll
    for (int r = 0; r < 4; ++r) {
      float rs = rsum[r];
#pragma unroll
      for (int mm = 1; mm < 16; mm <<= 1) rs += __shfl_xor(rs, mm);
      l_run[r] += rs;
    }
    bf16x8 pa[2];
#pragma unroll
    for (int w2 = 0; w2 < 2; ++w2) {
      const int blk = (w2 * 4 + q4) ^ (l16 & 7);
      pa[w2] = *reinterpret_cast<const bf16x8*>(&pw[l16 * 64 + blk * 8]);
    }
#pragma unroll
    for (int f = 0; f < 4; ++f) {
#pragma unroll
      for (int w2 = 0; w2 < 2; ++w2) {
        const bf16x8 vf = *reinterpret_cast<const bf16x8*>(
            vbase + (size_t)(f * 16 + l16) * NSEQ + j0 + w2 * 32 + q4 * 8);
        acc[f] = MFMA16(pa[w2], vf, acc[f]);
      }
    }
  };

  float hA[16], hB[16];
  LOADH(0, hA);
  for (int jt = 0; jt < 16; jt += 2) {
    LOADH(jt + 1, hB);
    BODY(jt, hA);
    if (jt + 2 < 16) LOADH(jt + 2, hA);
    BODY(jt + 1, hB);
  }

  const int b = bh / NHEADS, head = bh % NHEADS;
  float inv[4];
#pragma unroll
  for (int r = 0; r < 4; ++r) inv[r] = 1.f / l_run[r];
#pragma unroll
  for (int f = 0; f < 4; ++f) {
#pragma unroll
    for (int r = 0; r < 4; ++r) {
      const int gi = i0 + q4 * 4 + r;
      attn_out[((size_t)b * NSEQ + gi) * DIMM + head * DH + f * 16 + l16] =
          (bf16)(acc[f][r] * inv[r]);
    }
  }
}

// -------- output projection: attn_out(8192x768) @ woutT + b_out -> f32 out --------
__global__ __launch_bounds__(256) void oproj_gemm(
    const bf16* __restrict__ ain, const bf16* __restrict__ wT,
    const float* __restrict__ bias, float* __restrict__ out) {
  __shared__ __align__(16) bf16 As[128 * 32];
  __shared__ __align__(16) bf16 Bs[64 * 32];
  const int tid = threadIdx.x;
  const int wv = tid >> 6, l = tid & 63;
  const int l16 = l & 15, q4 = l >> 4;
  const int c0 = blockIdx.x * 64, row0 = blockIdx.y * 128;
  const int sr = tid >> 2, skk = (tid & 3) * 8;
  f32x4 acc0[4], acc1[4];
#pragma unroll
  for (int c = 0; c < 4; ++c) {
    acc0[c] = f32x4{0.f, 0.f, 0.f, 0.f};
    acc1[c] = f32x4{0.f, 0.f, 0.f, 0.f};
  }
  for (int k0 = 0; k0 < DIMM; k0 += 32) {
    __syncthreads();
    load_lds16(ain + (size_t)(row0 + sr) * DIMM + k0 + skk, As + tid * 8);
    load_lds16(ain + (size_t)(row0 + 64 + sr) * DIMM + k0 + skk, As + 2048 + tid * 8);
    load_lds16(wT + (size_t)(c0 + sr) * DIMM + k0 + skk, Bs + tid * 8);
    __syncthreads();
    const bf16x8 a0 = *reinterpret_cast<const bf16x8*>(&As[(wv * 32 + l16) * 32 + q4 * 8]);
    const bf16x8 a1 = *reinterpret_cast<const bf16x8*>(&As[(wv * 32 + 16 + l16) * 32 + q4 * 8]);
#pragma unroll
    for (int c = 0; c < 4; ++c) {
      const bf16x8 bb = *reinterpret_cast<const bf16x8*>(&Bs[(c * 16 + l16) * 32 + q4 * 8]);
      acc0[c] = MFMA16(a0, bb, acc0[c]);
      acc1[c] = MFMA16(a1, bb, acc1[c]);
    }
  }
#pragma unroll
  for (int c = 0; c < 4; ++c) {
    const int gc = c0 + c * 16 + l16;
    const float bv = bias[gc];
#pragma unroll
    for (int r = 0; r < 4; ++r) {
      out[(size_t)(row0 + wv * 32 + q4 * 4 + r) * DIMM + gc] = acc0[c][r] + bv;
      out[(size_t)(row0 + wv * 32 + 16 + q4 * 4 + r) * DIMM + gc] = acc1[c][r] + bv;
    }
  }
}

extern "C" void kernel_launch(void* const* d_in, const int* in_sizes, int n_in,
                              void* d_out, int out_size, void* d_ws, size_t ws_size,
                              hipStream_t stream) {
  const float* x = (const float*)d_in[0];
  const float* h = (const float*)d_in[1];
  const float* gamma = (const float*)d_in[2];
  const float* beta = (const float*)d_in[3];
  const float* w_qkv = (const float*)d_in[4];
  const float* w_out = (const float*)d_in[5];
  const float* b_out = (const float*)d_in[6];
  float* out = (float*)d_out;
  float* blended = out + (size_t)NB * NSEQ * DIMM;

  char* ws = (char*)d_ws;
  bf16* xn = (bf16*)(ws);                   // 12.6 MB; reused as attn_out after qkv_gemm
  bf16* qb = (bf16*)(ws + 12582912);
  bf16* kb = (bf16*)(ws + 25165824);
  bf16* vt = (bf16*)(ws + 37748736);
  bf16* wqkvT = (bf16*)(ws + 50331648);
  bf16* woutT = (bf16*)(ws + 53870592);

  hipLaunchKernelGGL(ln_kernel, dim3(2048), dim3(256), 0, stream, x, gamma, beta, xn);
  hipLaunchKernelGGL(tcast_kernel, dim3(72, 24), dim3(256), 0, stream, w_qkv, wqkvT, DIMM, NQKV);
  hipLaunchKernelGGL(tcast_kernel, dim3(24, 24), dim3(256), 0, stream, w_out, woutT, DIMM, DIMM);
  hipLaunchKernelGGL(qkv_gemm, dim3(36, 64), dim3(256), 0, stream, xn, wqkvT, qb, kb, vt);
  hipLaunchKernelGGL(attn_kernel, dim3(16, 96), dim3(256), 0, stream, qb, kb, vt, h, blended, xn);
  hipLaunchKernelGGL(oproj_gemm, dim3(12, 64), dim3(256), 0, stream, xn, woutT, b_out, out);
}

// Round 3
// 397.666 us; speedup vs baseline: 1.1697x; 1.1697x over previous
//
#include <hip/hip_runtime.h>
#include <hip/hip_bf16.h>
#include <stdint.h>

#define NB 8
#define NSEQ 1024
#define DIMM 768
#define NHEADS 12
#define DH 64
#define NQKV 2304
#define ALPHA_ 0.25f
#define SCALE_ 0.125f
#define EPS_ 1e-5f

typedef __bf16 bf16;
typedef bf16 bf16x8 __attribute__((ext_vector_type(8)));
typedef bf16 bf16x4 __attribute__((ext_vector_type(4)));
typedef float f32x4 __attribute__((ext_vector_type(4)));

#define MFMA16(a, b, c) __builtin_amdgcn_mfma_f32_16x16x32_bf16((a), (b), (c), 0, 0, 0)

static __device__ __forceinline__ void load_lds16(const void* gsrc, void* ldst) {
  __builtin_amdgcn_global_load_lds(
      (__attribute__((address_space(1))) void*)gsrc,
      (__attribute__((address_space(3))) void*)ldst, 16, 0, 0);
}

// barrier that does NOT drain vmcnt (preserves in-flight global_load_lds)
#define BAR_LGKM()                                             \
  do {                                                         \
    __builtin_amdgcn_sched_barrier(0);                         \
    asm volatile("s_waitcnt lgkmcnt(0)" ::: "memory");         \
    __builtin_amdgcn_s_barrier();                              \
    __builtin_amdgcn_sched_barrier(0);                         \
  } while (0)

// full drain + barrier (buffer handoff point)
#define BAR_FULL()                                                   \
  do {                                                               \
    __builtin_amdgcn_sched_barrier(0);                               \
    asm volatile("s_waitcnt vmcnt(0) lgkmcnt(0)" ::: "memory");      \
    __builtin_amdgcn_s_barrier();                                    \
    __builtin_amdgcn_sched_barrier(0);                               \
  } while (0)

// ---------------- LayerNorm + bf16 cast: x(8192x768) -> xn bf16 ----------------
__global__ __launch_bounds__(256) void ln_kernel(
    const float* __restrict__ x, const float* __restrict__ gamma,
    const float* __restrict__ beta, bf16* __restrict__ xn) {
  const int row = blockIdx.x * 4 + (threadIdx.x >> 6);
  const int lane = threadIdx.x & 63;
  const float* xr = x + (size_t)row * DIMM;
  float4 v[3];
  float s = 0.f, s2 = 0.f;
#pragma unroll
  for (int c = 0; c < 3; ++c) {
    v[c] = *reinterpret_cast<const float4*>(xr + c * 256 + lane * 4);
    s += v[c].x + v[c].y + v[c].z + v[c].w;
    s2 += v[c].x * v[c].x + v[c].y * v[c].y + v[c].z * v[c].z + v[c].w * v[c].w;
  }
#pragma unroll
  for (int m = 1; m < 64; m <<= 1) {
    s += __shfl_xor(s, m);
    s2 += __shfl_xor(s2, m);
  }
  const float mu = s * (1.f / DIMM);
  const float rstd = rsqrtf(s2 * (1.f / DIMM) - mu * mu + EPS_);
#pragma unroll
  for (int c = 0; c < 3; ++c) {
    const float4 g4 = *reinterpret_cast<const float4*>(gamma + c * 256 + lane * 4);
    const float4 b4 = *reinterpret_cast<const float4*>(beta + c * 256 + lane * 4);
    bf16x4 o;
    o[0] = (bf16)((v[c].x - mu) * rstd * g4.x + b4.x);
    o[1] = (bf16)((v[c].y - mu) * rstd * g4.y + b4.y);
    o[2] = (bf16)((v[c].z - mu) * rstd * g4.z + b4.z);
    o[3] = (bf16)((v[c].w - mu) * rstd * g4.w + b4.w);
    *reinterpret_cast<bf16x4*>(xn + (size_t)row * DIMM + c * 256 + lane * 4) = o;
  }
}

// ------------- transpose + cast: f32 in[R][C] -> bf16 out[C][R] -------------
__global__ __launch_bounds__(256) void tcast_kernel(
    const float* __restrict__ in, bf16* __restrict__ out, int R, int C) {
  __shared__ float tile[32][33];
  const int tx = threadIdx.x & 31, ty = threadIdx.x >> 5;
  const int c0 = blockIdx.x * 32, r0 = blockIdx.y * 32;
#pragma unroll
  for (int i = ty; i < 32; i += 8)
    tile[i][tx] = in[(size_t)(r0 + i) * C + c0 + tx];
  __syncthreads();
#pragma unroll
  for (int i = ty; i < 32; i += 8)
    out[(size_t)(c0 + i) * R + r0 + tx] = (bf16)tile[tx][i];
}

// -------- QKV GEMM: xn(8192x768) @ wT(2304 cols x 768 k) -> q,k,vT bf16 --------
__global__ __launch_bounds__(256) void qkv_gemm(
    const bf16* __restrict__ xn, const bf16* __restrict__ wT,
    bf16* __restrict__ qb, bf16* __restrict__ kb, bf16* __restrict__ vt) {
  __shared__ __align__(16) bf16 As[128 * 32];
  __shared__ __align__(16) bf16 Bs[64 * 32];
  const int tid = threadIdx.x;
  const int wv = tid >> 6, l = tid & 63;
  const int l16 = l & 15, q4 = l >> 4;
  const int c0 = blockIdx.x * 64, row0 = blockIdx.y * 128;
  const int sr = tid >> 2, skk = (tid & 3) * 8;
  f32x4 acc0[4], acc1[4];
#pragma unroll
  for (int c = 0; c < 4; ++c) {
    acc0[c] = f32x4{0.f, 0.f, 0.f, 0.f};
    acc1[c] = f32x4{0.f, 0.f, 0.f, 0.f};
  }
  for (int k0 = 0; k0 < DIMM; k0 += 32) {
    __syncthreads();
    load_lds16(xn + (size_t)(row0 + sr) * DIMM + k0 + skk, As + tid * 8);
    load_lds16(xn + (size_t)(row0 + 64 + sr) * DIMM + k0 + skk, As + 2048 + tid * 8);
    load_lds16(wT + (size_t)(c0 + sr) * DIMM + k0 + skk, Bs + tid * 8);
    __syncthreads();
    const bf16x8 a0 = *reinterpret_cast<const bf16x8*>(&As[(wv * 32 + l16) * 32 + q4 * 8]);
    const bf16x8 a1 = *reinterpret_cast<const bf16x8*>(&As[(wv * 32 + 16 + l16) * 32 + q4 * 8]);
#pragma unroll
    for (int c = 0; c < 4; ++c) {
      const bf16x8 bb = *reinterpret_cast<const bf16x8*>(&Bs[(c * 16 + l16) * 32 + q4 * 8]);
      acc0[c] = MFMA16(a0, bb, acc0[c]);
      acc1[c] = MFMA16(a1, bb, acc1[c]);
    }
  }
  const int sect = c0 / DIMM;          // 0=q 1=k 2=v (uniform per block)
  const int head = (c0 % DIMM) >> 6;   // uniform per block
#pragma unroll
  for (int c = 0; c < 4; ++c) {
    const int dd = c * 16 + l16;
#pragma unroll
    for (int r = 0; r < 4; ++r) {
#pragma unroll
      for (int rsub = 0; rsub < 2; ++rsub) {
        const int gm = row0 + wv * 32 + rsub * 16 + q4 * 4 + r;
        const int b = gm >> 10, n = gm & 1023;
        const size_t bhh = (size_t)b * NHEADS + head;
        const float av = rsub ? acc1[c][r] : acc0[c][r];
        const bf16 val = (bf16)av;
        if (sect == 0)      qb[(bhh * NSEQ + n) * DH + dd] = val;
        else if (sect == 1) kb[(bhh * NSEQ + n) * DH + dd] = val;
        else                vt[(bhh * DH + dd) * NSEQ + n] = val;
      }
    }
  }
}

// -------- fused attention (row-streaming h/blended) --------
// Block: 16 Q-rows, full j. 4 waves, wave wv owns the 64-col strip wv*64 of
// each 256-col j-tile (4 tiles). h staged into LDS double-buffered via
// global_load_lds in 1KB-contiguous single-row bursts; blend done in-place in
// LDS; blended written back with 1KB-contiguous row stores. Softmax reductions
// combined across waves via small LDS arrays. O partials summed across waves
// at the end.
__global__ __launch_bounds__(256) void attn_kernel(
    const bf16* __restrict__ qb, const bf16* __restrict__ kb,
    const bf16* __restrict__ vt, const float* __restrict__ h,
    float* __restrict__ blended, bf16* __restrict__ attn_out) {
  __shared__ __align__(16) float h_lds[2][16][260];   // 33280 B (pad 4 -> bank spread)
  __shared__ __align__(16) bf16 pw_all[4][16 * 64];   // 8192 B, wave-private P
  __shared__ float wred_max[4][16];
  __shared__ float wred_sum[4][16];
  __shared__ float lfin[16];

  const int tid = threadIdx.x;
  const int wv = tid >> 6, l = tid & 63;
  const int l16 = l & 15, q4 = l >> 4;
  const int i0 = blockIdx.x * 16;
  const int bh = blockIdx.y;
  const float* hrow = h + ((size_t)bh << 20);
  float* brow = blended + ((size_t)bh << 20);
  const bf16* kbase = kb + (size_t)bh * NSEQ * DH;
  const bf16* vbase = vt + (size_t)bh * DH * NSEQ;
  const int jc0 = wv * 64;  // wave's column offset inside the 256-col tile

  // Q fragments (16 rows, k = 0..63)
  bf16x8 aq[2];
#pragma unroll
  for (int w2 = 0; w2 < 2; ++w2)
    aq[w2] = *reinterpret_cast<const bf16x8*>(
        qb + ((size_t)bh * NSEQ + i0 + l16) * DH + w2 * 32 + q4 * 8);

  f32x4 acc[4];
  float m_run[4], l_run[4];
#pragma unroll
  for (int r = 0; r < 4; ++r) { m_run[r] = -1e30f; l_run[r] = 0.f; }
#pragma unroll
  for (int f = 0; f < 4; ++f) acc[f] = f32x4{0.f, 0.f, 0.f, 0.f};

  bf16* pw = pw_all[wv];

  // stage jt-tile of h into buffer nb: wave stages its 4 rows, 1KB/row/inst
  auto STAGE = [&](int jtn, int nb) {
#pragma unroll
    for (int c = 0; c < 4; ++c) {
      const int row = wv * 4 + c;
      load_lds16(hrow + (size_t)(i0 + row) * NSEQ + jtn * 256 + l * 4,
                 &h_lds[nb][row][0]);
    }
  };

  STAGE(0, 0);

  for (int jt = 0; jt < 4; ++jt) {
    const int cur = jt & 1;
    const int j0 = jt * 256 + jc0;  // wave's global col base

    // ---- B: QK^T for this wave's 16x64 strip ----
    f32x4 s[4];
#pragma unroll
    for (int js = 0; js < 4; ++js) s[js] = f32x4{0.f, 0.f, 0.f, 0.f};
#pragma unroll
    for (int js = 0; js < 4; ++js) {
#pragma unroll
      for (int w2 = 0; w2 < 2; ++w2) {
        const bf16x8 kf = *reinterpret_cast<const bf16x8*>(
            kbase + (size_t)(j0 + js * 16 + l16) * DH + w2 * 32 + q4 * 8);
        s[js] = MFMA16(aq[w2], kf, s[js]);
      }
    }

    // ---- C: handoff barrier — all waves' DMAs for buf[cur] retired ----
    BAR_FULL();

    // ---- A: stage next tile (overlaps the rest of this iteration) ----
    if (jt < 3) STAGE(jt + 1, cur ^ 1);

    // ---- D: blend in place in LDS, keep vals in regs, track strip max ----
    float bl[4][4];
    float tmax[4] = {-1e30f, -1e30f, -1e30f, -1e30f};
#pragma unroll
    for (int js = 0; js < 4; ++js) {
#pragma unroll
      for (int r = 0; r < 4; ++r) {
        float* hp = &h_lds[cur][q4 * 4 + r][jc0 + js * 16 + l16];
        const float val = s[js][r] * (ALPHA_ * SCALE_) + 0.75f * (*hp);
        *hp = val;
        bl[js][r] = val;
        tmax[r] = fmaxf(tmax[r], val);
      }
    }
    // ---- E: strip max across 16 lanes, publish per-wave row max ----
#pragma unroll
    for (int r = 0; r < 4; ++r) {
#pragma unroll
      for (int mm = 1; mm < 16; mm <<= 1)
        tmax[r] = fmaxf(tmax[r], __shfl_xor(tmax[r], mm));
    }
    if (l16 == 0) {
#pragma unroll
      for (int r = 0; r < 4; ++r) wred_max[wv][q4 * 4 + r] = tmax[r];
    }
    BAR_LGKM();

    // ---- G: combined max, rescale, exp, write P, publish per-wave sums ----
    float rsum[4];
#pragma unroll
    for (int r = 0; r < 4; ++r) {
      const int row = q4 * 4 + r;
      const float mt = fmaxf(fmaxf(wred_max[0][row], wred_max[1][row]),
                             fmaxf(wred_max[2][row], wred_max[3][row]));
      const float mnew = fmaxf(m_run[r], mt);
      const float sc = __expf(m_run[r] - mnew);
      m_run[r] = mnew;
      l_run[r] *= sc;
#pragma unroll
      for (int f = 0; f < 4; ++f) acc[f][r] *= sc;
      rsum[r] = 0.f;
#pragma unroll
      for (int js = 0; js < 4; ++js) {
        const float p = __expf(bl[js][r] - mnew);
        rsum[r] += p;
        const int blk = (js * 2 + (l16 >> 3)) ^ (row & 7);
        pw[row * 64 + blk * 8 + (l16 & 7)] = (bf16)p;
      }
    }
#pragma unroll
    for (int r = 0; r < 4; ++r) {
      float rs = rsum[r];
#pragma unroll
      for (int mm = 1; mm < 16; mm <<= 1) rs += __shfl_xor(rs, mm);
      if (l16 == 0) wred_sum[wv][q4 * 4 + r] = rs;
    }
    BAR_LGKM();

    // ---- H: finalize l, P @ V for this strip ----
#pragma unroll
    for (int r = 0; r < 4; ++r) {
      const int row = q4 * 4 + r;
      l_run[r] += wred_sum[0][row] + wred_sum[1][row] +
                  wred_sum[2][row] + wred_sum[3][row];
    }
    bf16x8 pa[2];
#pragma unroll
    for (int w2 = 0; w2 < 2; ++w2) {
      const int blk = (w2 * 4 + q4) ^ (l16 & 7);
      pa[w2] = *reinterpret_cast<const bf16x8*>(&pw[l16 * 64 + blk * 8]);
    }
#pragma unroll
    for (int f = 0; f < 4; ++f) {
#pragma unroll
      for (int w2 = 0; w2 < 2; ++w2) {
        const bf16x8 vf = *reinterpret_cast<const bf16x8*>(
            vbase + (size_t)(f * 16 + l16) * NSEQ + jt * 256 + jc0 + w2 * 32 + q4 * 8);
        acc[f] = MFMA16(pa[w2], vf, acc[f]);
      }
    }

    // ---- I: blended store-out, 1KB contiguous per row (wave's 4 rows) ----
#pragma unroll
    for (int c = 0; c < 4; ++c) {
      const int row = wv * 4 + c;
      const float4 vv = *reinterpret_cast<const float4*>(&h_lds[cur][row][l * 4]);
      *reinterpret_cast<float4*>(brow + (size_t)(i0 + row) * NSEQ + jt * 256 + l * 4) = vv;
    }
  }

  // ---- epilogue: cross-wave O sum, normalize, write attn_out ----
  if (wv == 0 && l16 == 0) {
#pragma unroll
    for (int r = 0; r < 4; ++r) lfin[q4 * 4 + r] = l_run[r];
  }
  float* ored = &h_lds[0][0][0];  // [4][16][64] f32, reuses h buffer
#pragma unroll
  for (int f = 0; f < 4; ++f) {
#pragma unroll
    for (int r = 0; r < 4; ++r)
      ored[(wv * 16 + q4 * 4 + r) * 64 + f * 16 + l16] = acc[f][r];
  }
  BAR_LGKM();
  const int b = bh / NHEADS, head = bh % NHEADS;
#pragma unroll
  for (int c = 0; c < 4; ++c) {
    const int row = wv * 4 + c;
    float o = ored[(0 * 16 + row) * 64 + l] + ored[(1 * 16 + row) * 64 + l] +
              ored[(2 * 16 + row) * 64 + l] + ored[(3 * 16 + row) * 64 + l];
    o *= 1.f / lfin[row];
    attn_out[((size_t)b * NSEQ + i0 + row) * DIMM + head * DH + l] = (bf16)o;
  }
}

// -------- output projection: attn_out(8192x768) @ woutT + b_out -> f32 out --------
__global__ __launch_bounds__(256) void oproj_gemm(
    const bf16* __restrict__ ain, const bf16* __restrict__ wT,
    const float* __restrict__ bias, float* __restrict__ out) {
  __shared__ __align__(16) bf16 As[128 * 32];
  __shared__ __align__(16) bf16 Bs[64 * 32];
  const int tid = threadIdx.x;
  const int wv = tid >> 6, l = tid & 63;
  const int l16 = l & 15, q4 = l >> 4;
  const int c0 = blockIdx.x * 64, row0 = blockIdx.y * 128;
  const int sr = tid >> 2, skk = (tid & 3) * 8;
  f32x4 acc0[4], acc1[4];
#pragma unroll
  for (int c = 0; c < 4; ++c) {
    acc0[c] = f32x4{0.f, 0.f, 0.f, 0.f};
    acc1[c] = f32x4{0.f, 0.f, 0.f, 0.f};
  }
  for (int k0 = 0; k0 < DIMM; k0 += 32) {
    __syncthreads();
    load_lds16(ain + (size_t)(row0 + sr) * DIMM + k0 + skk, As + tid * 8);
    load_lds16(ain + (size_t)(row0 + 64 + sr) * DIMM + k0 + skk, As + 2048 + tid * 8);
    load_lds16(wT + (size_t)(c0 + sr) * DIMM + k0 + skk, Bs + tid * 8);
    __syncthreads();
    const bf16x8 a0 = *reinterpret_cast<const bf16x8*>(&As[(wv * 32 + l16) * 32 + q4 * 8]);
    const bf16x8 a1 = *reinterpret_cast<const bf16x8*>(&As[(wv * 32 + 16 + l16) * 32 + q4 * 8]);
#pragma unroll
    for (int c = 0; c < 4; ++c) {
      const bf16x8 bb = *reinterpret_cast<const bf16x8*>(&Bs[(c * 16 + l16) * 32 + q4 * 8]);
      acc0[c] = MFMA16(a0, bb, acc0[c]);
      acc1[c] = MFMA16(a1, bb, acc1[c]);
    }
  }
#pragma unroll
  for (int c = 0; c < 4; ++c) {
    const int gc = c0 + c * 16 + l16;
    const float bv = bias[gc];
#pragma unroll
    for (int r = 0; r < 4; ++r) {
      out[(size_t)(row0 + wv * 32 + q4 * 4 + r) * DIMM + gc] = acc0[c][r] + bv;
      out[(size_t)(row0 + wv * 32 + 16 + q4 * 4 + r) * DIMM + gc] = acc1[c][r] + bv;
    }
  }
}

extern "C" void kernel_launch(void* const* d_in, const int* in_sizes, int n_in,
                              void* d_out, int out_size, void* d_ws, size_t ws_size,
                              hipStream_t stream) {
  const float* x = (const float*)d_in[0];
  const float* h = (const float*)d_in[1];
  const float* gamma = (const float*)d_in[2];
  const float* beta = (const float*)d_in[3];
  const float* w_qkv = (const float*)d_in[4];
  const float* w_out = (const float*)d_in[5];
  const float* b_out = (const float*)d_in[6];
  float* out = (float*)d_out;
  float* blended = out + (size_t)NB * NSEQ * DIMM;

  char* ws = (char*)d_ws;
  bf16* xn = (bf16*)(ws);                   // 12.6 MB; reused as attn_out after qkv_gemm
  bf16* qb = (bf16*)(ws + 12582912);
  bf16* kb = (bf16*)(ws + 25165824);
  bf16* vt = (bf16*)(ws + 37748736);
  bf16* wqkvT = (bf16*)(ws + 50331648);
  bf16* woutT = (bf16*)(ws + 53870592);

  hipLaunchKernelGGL(ln_kernel, dim3(2048), dim3(256), 0, stream, x, gamma, beta, xn);
  hipLaunchKernelGGL(tcast_kernel, dim3(72, 24), dim3(256), 0, stream, w_qkv, wqkvT, DIMM, NQKV);
  hipLaunchKernelGGL(tcast_kernel, dim3(24, 24), dim3(256), 0, stream, w_out, woutT, DIMM, DIMM);
  hipLaunchKernelGGL(qkv_gemm, dim3(36, 64), dim3(256), 0, stream, xn, wqkvT, qb, kb, vt);
  hipLaunchKernelGGL(attn_kernel, dim3(64, 96), dim3(256), 0, stream, qb, kb, vt, h, blended, xn);
  hipLaunchKernelGGL(oproj_gemm, dim3(12, 64), dim3(256), 0, stream, xn, woutT, b_out, out);
}